// Round 8
// baseline (291.745 us; speedup 1.0000x reference)
//
#include <hip/hip_runtime.h>
#include <hip/hip_bf16.h>
#include <math.h>

#define B_    2
#define N_    2048
#define DIM_  1024
#define H_    16
#define HD_   64
#define EPS_  1e-5f
#define SCALE_ 0.125f   // HD_^-0.5
#define LOG2E_ 1.4426950408889634f
#define MFIX_  14.0f    // fixed softmax max (log2 domain); |logit| <= 11.7 hard bound

typedef __attribute__((ext_vector_type(8))) __bf16 bf16x8;
typedef __attribute__((ext_vector_type(8))) unsigned short ushort8;
typedef __attribute__((ext_vector_type(4))) float f32x4;
typedef __attribute__((ext_vector_type(4))) unsigned int uint4v;

__device__ __forceinline__ unsigned short f2bf(float x) {
    unsigned u = __builtin_bit_cast(unsigned, x);
    u += 0x7fff + ((u >> 16) & 1);   // RNE
    return (unsigned short)(u >> 16);
}
// pack two floats to bf16x2 with round-half-up (+0x8000) via v_perm
__device__ __forceinline__ unsigned pk2bf(float a, float b) {
    unsigned ua = __builtin_bit_cast(unsigned, a) + 0x8000u;
    unsigned ub = __builtin_bit_cast(unsigned, b) + 0x8000u;
    return __builtin_amdgcn_perm(ub, ua, 0x07060302);
}
// pack two floats to bf16x2 with RNE in ONE instruction (gfx950)
__device__ __forceinline__ unsigned cvtpk(float a, float b) {
    unsigned r;
    asm("v_cvt_pk_bf16_f32 %0, %1, %2" : "=v"(r) : "v"(a), "v"(b));
    return r;
}

__device__ __forceinline__ void gl_lds16(const void* g, void* l) {
    __builtin_amdgcn_global_load_lds(
        (const __attribute__((address_space(1))) void*)g,
        (__attribute__((address_space(3))) void*)l, 16, 0, 0);
}

// ---------------------------------------------------------------------------
// Fused fp32 -> bf16 cast of [x | qkv_w | proj_w] into one contiguous region.
// ---------------------------------------------------------------------------
__global__ __launch_bounds__(256) void cast_all_bf16(
    const float* __restrict__ x, const float* __restrict__ qkvw,
    const float* __restrict__ pw, unsigned short* __restrict__ out) {
    int i = (blockIdx.x * 256 + threadIdx.x) * 8;
    const float* src;
    if (i < 4194304) src = x + i;
    else if (i < 7340032) src = qkvw + (i - 4194304);
    else src = pw + (i - 7340032);
    float4 v0 = *(const float4*)src;
    float4 v1 = *(const float4*)(src + 4);
    ushort8 r;
    r[0] = f2bf(v0.x); r[1] = f2bf(v0.y); r[2] = f2bf(v0.z); r[3] = f2bf(v0.w);
    r[4] = f2bf(v1.x); r[5] = f2bf(v1.y); r[6] = f2bf(v1.z); r[7] = f2bf(v1.w);
    *(ushort8*)(out + i) = r;
}

// ---------------------------------------------------------------------------
// Pack int32 mask (B,N,N) -> bitmask (B,N,N/64) uint64. One wave per word.
// ---------------------------------------------------------------------------
__global__ __launch_bounds__(256) void pack_mask(
    const int* __restrict__ mask, unsigned long long* __restrict__ bm) {
    int w = blockIdx.x * 4 + (threadIdx.x >> 6);
    int lane = threadIdx.x & 63;
    int mv = mask[(size_t)w * 64 + lane];
    unsigned long long bits = __ballot(mv != 0);
    if (lane == 0) bm[w] = bits;
}

// ---------------------------------------------------------------------------
// GEMM1 + fused LayerNorm epilogue + FUSED V-transpose (confirmed good, R4).
// ---------------------------------------------------------------------------
__global__ __launch_bounds__(256) void gemm_qkv_ln(
    const unsigned short* __restrict__ A, const unsigned short* __restrict__ Bw,
    const float* __restrict__ qnw, const float* __restrict__ qnb,
    const float* __restrict__ knw, const float* __restrict__ knb,
    unsigned short* __restrict__ qbuf, unsigned short* __restrict__ kbuf,
    unsigned short* __restrict__ vt) {
    const int K = DIM_;
    __shared__ unsigned short As[128 * 32];
    __shared__ unsigned short Bs[128 * 32];
    const int tid = threadIdx.x;
    const int wave = tid >> 6, lane = tid & 63;
    const int quad = lane >> 4, lcol = lane & 15;
    const int wr = wave >> 1, wc = wave & 1;
    const int row0 = blockIdx.y * 128, col0 = blockIdx.x * 128;

    f32x4 acc[4][4];
#pragma unroll
    for (int i = 0; i < 4; ++i)
#pragma unroll
        for (int j = 0; j < 4; ++j) acc[i][j] = (f32x4){0.f, 0.f, 0.f, 0.f};

    for (int k0 = 0; k0 < K; k0 += 32) {
        __syncthreads();
#pragma unroll
        for (int c = 0; c < 2; ++c) {
            int base = wave * 2048 + c * 1024;
            int myofs = base + lane * 16;
            int r = myofs >> 6;
            int kb = myofs & 63;
            gl_lds16((const char*)A + ((size_t)(row0 + r) * K + k0) * 2 + kb,
                     (char*)As + base);
            gl_lds16((const char*)Bw + ((size_t)(col0 + r) * K + k0) * 2 + kb,
                     (char*)Bs + base);
        }
        __syncthreads();

        bf16x8 af[4], bfr[4];
#pragma unroll
        for (int i = 0; i < 4; ++i) {
            af[i] = *(const bf16x8*)&As[(wr * 64 + i * 16 + lcol) * 32 + quad * 8];
            bfr[i] = *(const bf16x8*)&Bs[(wc * 64 + i * 16 + lcol) * 32 + quad * 8];
        }
#pragma unroll
        for (int i = 0; i < 4; ++i)
#pragma unroll
            for (int j = 0; j < 4; ++j)
                acc[i][j] = __builtin_amdgcn_mfma_f32_16x16x32_bf16(
                    af[i], bfr[j], acc[i][j], 0, 0, 0);
    }

    const int colbase = col0 + wc * 64;      // wave-uniform, one head
    const int t = colbase >> 10;             // 0=q, 1=k, 2=v
    const int h = (colbase & 1023) >> 6;

    if (t < 2) {
        const float* wv = (t == 0) ? qnw : knw;
        const float* bv = (t == 0) ? qnb : knb;
        float wreg[4], breg[4];
#pragma unroll
        for (int j = 0; j < 4; ++j) {
            wreg[j] = wv[j * 16 + lcol];
            breg[j] = bv[j * 16 + lcol];
        }
        const float sc = (t == 0) ? (SCALE_ * LOG2E_) : 1.f;
        unsigned short* obase = (t == 0) ? qbuf : kbuf;
#pragma unroll
        for (int i = 0; i < 4; ++i) {
#pragma unroll
            for (int reg = 0; reg < 4; ++reg) {
                int row = row0 + wr * 64 + i * 16 + quad * 4 + reg;
                int bb = row >> 11, n = row & (N_ - 1);
                float v[4];
#pragma unroll
                for (int j = 0; j < 4; ++j) v[j] = acc[i][j][reg];
                float s = v[0] + v[1] + v[2] + v[3];
                s += __shfl_xor(s, 1);
                s += __shfl_xor(s, 2);
                s += __shfl_xor(s, 4);
                s += __shfl_xor(s, 8);
                float mu = s * (1.f / 64.f);
                float d[4], s2 = 0.f;
#pragma unroll
                for (int j = 0; j < 4; ++j) {
                    d[j] = v[j] - mu;
                    s2 += d[j] * d[j];
                }
                s2 += __shfl_xor(s2, 1);
                s2 += __shfl_xor(s2, 2);
                s2 += __shfl_xor(s2, 4);
                s2 += __shfl_xor(s2, 8);
                float r = rsqrtf(s2 * (1.f / 64.f) + EPS_);
                float o0 = (d[0] * r * wreg[0] + breg[0]) * sc;
                float o1 = (d[1] * r * wreg[1] + breg[1]) * sc;
                float o2 = (d[2] * r * wreg[2] + breg[2]) * sc;
                float o3 = (d[3] * r * wreg[3] + breg[3]) * sc;
                uint2 pk;
                pk.x = pk2bf(o0, o1);
                pk.y = pk2bf(o2, o3);
                // sigma store: positions lcol*4 + j, one uint2 per lane
                *(uint2*)(obase + ((size_t)(bb * H_ + h) * N_ + n) * 64 +
                          lcol * 4) = pk;
            }
        }
    } else {
        // V: fused transpose into vt (B,H,D,N), PV-ready key permutation.
        const int rowb = row0 + wr * 64;
        const int bb = rowb >> 11;
        unsigned short* vtb =
            vt + ((size_t)(bb * H_ + h) * 64) * (size_t)N_ + (rowb & (N_ - 1));
#pragma unroll
        for (int i = 0; i < 4; ++i) {
            const int pos = (i >> 1) * 32 + quad * 8 + (i & 1) * 4;
#pragma unroll
            for (int jj = 0; jj < 4; ++jj) {
                uint2 pk;
                pk.x = pk2bf(acc[i][jj][0], acc[i][jj][1]);
                pk.y = pk2bf(acc[i][jj][2], acc[i][jj][3]);
                *(uint2*)(vtb + (size_t)(lcol + 16 * jj) * N_ + pos) = pk;
            }
        }
    }
}

// ---------------------------------------------------------------------------
// Output projection GEMM: C[4096,1024] = A[4096,1024] * Bw[1024,1024]^T + b.
// ---------------------------------------------------------------------------
__global__ __launch_bounds__(256) void gemm_proj(
    const unsigned short* __restrict__ A, const unsigned short* __restrict__ Bw,
    const float* __restrict__ bias, float* __restrict__ Cout) {
    const int K = DIM_;
    __shared__ unsigned short As[128 * 32];  // 8 KB, 8 planes
    __shared__ unsigned short Bs[64 * 32];   // 4 KB, 4 planes
    const int tid = threadIdx.x;
    const int wave = tid >> 6, lane = tid & 63;
    const int quad = lane >> 4, lcol = lane & 15;
    const int row0 = blockIdx.y * 128, col0 = blockIdx.x * 64;

    f32x4 acc[2][4];
#pragma unroll
    for (int i = 0; i < 2; ++i)
#pragma unroll
        for (int j = 0; j < 4; ++j) acc[i][j] = (f32x4){0.f, 0.f, 0.f, 0.f};

    for (int k0 = 0; k0 < K; k0 += 32) {
        __syncthreads();
#pragma unroll
        for (int pi = 0; pi < 3; ++pi) {
            int p = wave * 3 + pi;  // 12 planes: 0..7 = A, 8..11 = B
            if (p < 8) {
                int base = p * 1024;
                int myofs = base + lane * 16;
                int r = myofs >> 6, kb = myofs & 63;
                gl_lds16((const char*)A + ((size_t)(row0 + r) * K + k0) * 2 + kb,
                         (char*)As + base);
            } else {
                int base = (p - 8) * 1024;
                int myofs = base + lane * 16;
                int r = myofs >> 6, kb = myofs & 63;
                gl_lds16((const char*)Bw + ((size_t)(col0 + r) * K + k0) * 2 + kb,
                         (char*)Bs + base);
            }
        }
        __syncthreads();

        bf16x8 af[2], bfr[4];
#pragma unroll
        for (int i = 0; i < 2; ++i)
            af[i] = *(const bf16x8*)&As[(wave * 32 + i * 16 + lcol) * 32 + quad * 8];
#pragma unroll
        for (int j = 0; j < 4; ++j)
            bfr[j] = *(const bf16x8*)&Bs[(j * 16 + lcol) * 32 + quad * 8];
#pragma unroll
        for (int i = 0; i < 2; ++i)
#pragma unroll
            for (int j = 0; j < 4; ++j)
                acc[i][j] = __builtin_amdgcn_mfma_f32_16x16x32_bf16(
                    af[i], bfr[j], acc[i][j], 0, 0, 0);
    }

#pragma unroll
    for (int i = 0; i < 2; ++i) {
#pragma unroll
        for (int j = 0; j < 4; ++j) {
            int col = col0 + j * 16 + lcol;
            float bv = bias[col];
#pragma unroll
            for (int reg = 0; reg < 4; ++reg) {
                int row = row0 + wave * 32 + i * 16 + quad * 4 + reg;
                Cout[(size_t)row * DIM_ + col] = acc[i][j][reg] + bv;
            }
        }
    }
}

// ---------------------------------------------------------------------------
// MFMA flash attention v13: 64 q-rows/wave (4x 16-row fragments). Rationale:
// v9's 12.5k-cyc/body wall vs ~3k of pipe demand = dependency-latency bound;
// the only lever that ever moved the plateau was work-per-wave (v6->v7 16->32
// rows: +15%). v13 doubles it again: every K/V ds_read now feeds FOUR 16-row
// MFMA fragments (4x chain ILP), per-CU staging volume halves (1 block/CU
// stages K/V once). 256-thr blocks, 4 waves x 64 rows = 256 q-rows/block,
// grid 8x32 = 256 blocks = 1/CU, 1 wave/SIMD, VGPR budget 512 (lb(256,1)).
// LDS: Q 32K + 4 x (K 8K + V 8K) = 96 KB -> 1 block/CU. Same v9 pipeline:
// 4 tile-buffers, pair-bodies, loads issued one full PAIR before their wait.
// ---------------------------------------------------------------------------
#define WAITBAR(Ncnt)                                                     \
    asm volatile("s_waitcnt vmcnt(" #Ncnt ")" ::: "memory");              \
    __builtin_amdgcn_s_barrier();                                         \
    __builtin_amdgcn_sched_barrier(0);

#define ISSUE2(B0, B1)                                                    \
    {                                                                     \
        gl_lds16(kp0, (char*)Ks[B0] + kld0);                              \
        gl_lds16(kp1, (char*)Ks[B0] + kld1);                              \
        gl_lds16(vp0, (char*)Vts[B0] + kld0);                             \
        gl_lds16(vp1, (char*)Vts[B0] + kld1);                             \
        gl_lds16(kp0 + 8192, (char*)Ks[B1] + kld0);                       \
        gl_lds16(kp1 + 8192, (char*)Ks[B1] + kld1);                       \
        gl_lds16(vp0 + 128, (char*)Vts[B1] + kld0);                       \
        gl_lds16(vp1 + 128, (char*)Vts[B1] + kld1);                       \
        _Pragma("unroll")                                                 \
        for (int qf = 0; qf < 4; ++qf) {                                  \
            mm[B0][qf] = bmq[qf][0];                                      \
            mm[B1][qf] = bmq[qf][1];                                      \
            bmq[qf] += 2;                                                 \
        }                                                                 \
        kp0 += 16384; kp1 += 16384; vp0 += 256; vp1 += 256;               \
    }

#define QKT(J, SACC, MROW)                                                \
    {                                                                     \
        _Pragma("unroll")                                                 \
        for (int qf = 0; qf < 4; ++qf) {                                  \
            unsigned long long mq = (MROW)[qf] >> (quad * 4);             \
            unsigned mlo = (unsigned)mq, mhi = (unsigned)(mq >> 32);      \
            _Pragma("unroll")                                             \
            for (int kt = 0; kt < 4; ++kt) {                              \
                unsigned word = (kt < 2) ? mlo : mhi;                     \
                _Pragma("unroll")                                         \
                for (int reg = 0; reg < 4; ++reg) {                       \
                    unsigned msk = (unsigned)(((int)(word <<              \
                        (31 - ((kt & 1) * 16 + reg)))) >> 31);            \
                    SACC[qf][kt][reg] = __builtin_bit_cast(float,         \
                        (msk & 0xc61c4000u) | (~msk & 0xc1600000u));      \
                }                                                         \
            }                                                             \
        }                                                                 \
        __builtin_amdgcn_s_setprio(1);                                    \
        _Pragma("unroll")                                                 \
        for (int kt = 0; kt < 4; ++kt)                                    \
            _Pragma("unroll")                                             \
            for (int d0 = 0; d0 < 2; ++d0) {                              \
                bf16x8 ak = *(const bf16x8*)((const char*)Ks[J] +         \
                    (d0 * 4 + quad) * 1024 + kt * 256 + lofs);            \
                _Pragma("unroll")                                         \
                for (int qf = 0; qf < 4; ++qf)                            \
                    SACC[qf][kt] = __builtin_amdgcn_mfma_f32_16x16x32_bf16( \
                        ak, bq[qf][d0], SACC[qf][kt], 0, 0, 0);           \
            }                                                             \
        __builtin_amdgcn_s_setprio(0);                                    \
    }

#define SM(SACC, PK)                                                      \
    _Pragma("unroll")                                                     \
    for (int qf = 0; qf < 4; ++qf)                                        \
        _Pragma("unroll")                                                 \
        for (int kt = 0; kt < 4; ++kt) {                                  \
            float p0 = exp2f(SACC[qf][kt][0]);                            \
            float p1 = exp2f(SACC[qf][kt][1]);                            \
            float p2 = exp2f(SACC[qf][kt][2]);                            \
            float p3 = exp2f(SACC[qf][kt][3]);                            \
            PK[qf][kt].x = cvtpk(p0, p1);                                 \
            PK[qf][kt].y = cvtpk(p2, p3);                                 \
        }

#define PV(J, PK)                                                         \
    {                                                                     \
        __builtin_amdgcn_s_setprio(1);                                    \
        _Pragma("unroll")                                                 \
        for (int P = 0; P < 2; ++P) {                                     \
            bf16x8 bp[4];                                                 \
            _Pragma("unroll")                                             \
            for (int qf = 0; qf < 4; ++qf) {                              \
                uint4v bu;                                                \
                bu[0] = PK[qf][2 * P].x;  bu[1] = PK[qf][2 * P].y;        \
                bu[2] = PK[qf][2 * P + 1].x; bu[3] = PK[qf][2 * P + 1].y; \
                bp[qf] = __builtin_bit_cast(bf16x8, bu);                  \
                lacc[qf] = __builtin_amdgcn_mfma_f32_16x16x32_bf16(       \
                    ones, bp[qf], lacc[qf], 0, 0, 0);                     \
            }                                                             \
            _Pragma("unroll")                                             \
            for (int dt = 0; dt < 4; ++dt) {                              \
                bf16x8 va = *(const bf16x8*)((const char*)Vts[J] +        \
                    (P * 4 + quad) * 1024 + dt * 256 + lofs);             \
                _Pragma("unroll")                                         \
                for (int qf = 0; qf < 4; ++qf)                            \
                    oacc[qf][dt] = __builtin_amdgcn_mfma_f32_16x16x32_bf16( \
                        va, bp[qf], oacc[qf][dt], 0, 0, 0);               \
            }                                                             \
        }                                                                 \
        __builtin_amdgcn_s_setprio(0);                                    \
    }

#define PAIR(J0, J1)                                                      \
    {                                                                     \
        f32x4 saccA[4][4], saccB[4][4];                                   \
        uint2 pkA[4][4], pkB[4][4];                                       \
        QKT(J0, saccA, mm[J0])                                            \
        SM(saccA, pkA)                                                    \
        QKT(J1, saccB, mm[J1])                                            \
        PV(J0, pkA)                                                       \
        SM(saccB, pkB)                                                    \
        PV(J1, pkB)                                                       \
    }

__global__ __launch_bounds__(256, 1) void flash_attn_mfma13(
    const unsigned short* __restrict__ q, const unsigned short* __restrict__ k,
    const unsigned short* __restrict__ vt,
    const unsigned long long* __restrict__ bm, unsigned short* __restrict__ ao) {
    __shared__ unsigned short Qs[256 * 64];       // 32 KB
    __shared__ unsigned short Ks[4][64 * 64];     // 32 KB
    __shared__ unsigned short Vts[4][64 * 64];    // 32 KB -> 96 KB total

    const int tid = threadIdx.x;
    const int wave = tid >> 6, lane = tid & 63;
    const int quad = lane >> 4, lcol = lane & 15;
    const int bh = blockIdx.y, b = bh >> 4, h = bh & 15;
    const int q0 = blockIdx.x * 256;
    const int lofs = (lcol ^ (quad * 2)) << 4;   // loop-invariant ds_read part

    const char* kgbase = (const char*)k + (size_t)bh * N_ * 128;
    const char* vtbase = (const char*)vt + (size_t)bh * 64 * N_ * 2;

    // per-wave staging (2 planes/wave for K and for V), incrementing pointers
    const int c0 = wave * 2, c1 = c0 + 1;
    const int swz0 = (c0 & 3) * 2, swz1 = (c1 & 3) * 2;
    const int kld0 = c0 * 1024, kld1 = c1 * 1024;
    const char* kp0 = kgbase + (lane ^ swz0) * 128 + c0 * 16;
    const char* kp1 = kgbase + (lane ^ swz1) * 128 + c1 * 16;
    const char* vp0 = vtbase + (size_t)(lane ^ swz0) * (N_ * 2) + c0 * 16;
    const char* vp1 = vtbase + (size_t)(lane ^ swz1) * (N_ * 2) + c1 * 16;

    // 4 mask streams, one per 16-row fragment
    const unsigned long long* bmq[4];
#pragma unroll
    for (int qf = 0; qf < 4; ++qf)
        bmq[qf] = bm + ((size_t)b * N_ + q0 + wave * 64 + qf * 16 + lcol) * 32;
    unsigned long long mm[4][4];   // [buf][qf]

    // ---- prologue: Q first (the 8 OLDEST vmem ops), then tiles 0..3
    {
        const char* qg = (const char*)(q + (size_t)(bh * N_ + q0) * 64);
#pragma unroll
        for (int c = 0; c < 8; ++c) {
            int base = wave * 8192 + c * 1024;
            gl_lds16(qg + base + lane * 16, (char*)Qs + base);
        }
    }
    asm volatile("" ::: "memory");
    __builtin_amdgcn_sched_barrier(0);
#pragma unroll
    for (int t = 0; t < 4; ++t) {
        gl_lds16(kp0, (char*)Ks[t] + kld0);
        gl_lds16(kp1, (char*)Ks[t] + kld1);
        gl_lds16(vp0, (char*)Vts[t] + kld0);
        gl_lds16(vp1, (char*)Vts[t] + kld1);
#pragma unroll
        for (int qf = 0; qf < 4; ++qf) mm[t][qf] = bmq[qf][t];
        kp0 += 8192; kp1 += 8192; vp0 += 128; vp1 += 128;
        __builtin_amdgcn_sched_barrier(0);
    }
#pragma unroll
    for (int qf = 0; qf < 4; ++qf) bmq[qf] += 4;
    // drain own Q (8 oldest of 40 outstanding: 8 Q + 16 gl_lds + 16 mask).
    // Each wave reads ONLY its own staged Q planes -> no barrier needed.
    asm volatile("s_waitcnt vmcnt(32)" ::: "memory");
    __builtin_amdgcn_sched_barrier(0);

    bf16x8 bq[4][2];
#pragma unroll
    for (int qf = 0; qf < 4; ++qf)
#pragma unroll
        for (int d0 = 0; d0 < 2; ++d0)
            bq[qf][d0] = *(const bf16x8*)&Qs[(wave * 64 + qf * 16 + lcol) * 64 +
                                             d0 * 32 + quad * 8];

    ushort8 ot;
#pragma unroll
    for (int i = 0; i < 8; ++i) ot[i] = 0x3F80;  // bf16 1.0
    const bf16x8 ones = __builtin_bit_cast(bf16x8, ot);

    f32x4 oacc[4][4];
#pragma unroll
    for (int qf = 0; qf < 4; ++qf)
#pragma unroll
        for (int dt = 0; dt < 4; ++dt) oacc[qf][dt] = (f32x4){0.f, 0.f, 0.f, 0.f};
    f32x4 lacc[4];
#pragma unroll
    for (int qf = 0; qf < 4; ++qf) lacc[qf] = (f32x4){0.f, 0.f, 0.f, 0.f};

    // ---- 16 pair-bodies over 32 tiles
    // body 0: tiles 0,1 (no issue; tiles 2,3 remain in flight: 16 ops)
    WAITBAR(16)
    PAIR(0, 1)
    for (int g = 0; g < 7; ++g) {
        WAITBAR(0)
        ISSUE2(0, 1)
        PAIR(2, 3)
        WAITBAR(0)
        ISSUE2(2, 3)
        PAIR(0, 1)
    }
    WAITBAR(0)
    PAIR(2, 3)

#pragma unroll
    for (int qf = 0; qf < 4; ++qf) {
        float inv = 1.f / lacc[qf][0];
        int row = q0 + wave * 64 + qf * 16 + lcol;
        unsigned short* dst =
            ao + ((size_t)(b * N_ + row)) * DIM_ + h * 64 + quad * 4;
#pragma unroll
        for (int dt = 0; dt < 4; ++dt) {
            uint2 pko;
            pko.x = pk2bf(oacc[qf][dt][0] * inv, oacc[qf][dt][1] * inv);
            pko.y = pk2bf(oacc[qf][dt][2] * inv, oacc[qf][dt][3] * inv);
            *(uint2*)(dst + dt * 16) = pko;
        }
    }
}

// ---------------------------------------------------------------------------
extern "C" void kernel_launch(void* const* d_in, const int* in_sizes, int n_in,
                              void* d_out, int out_size, void* d_ws,
                              size_t ws_size, hipStream_t stream) {
    const float* x     = (const float*)d_in[0];
    const int*   mask  = (const int*)d_in[1];
    const float* qkv_w = (const float*)d_in[2];
    const float* qnw   = (const float*)d_in[3];
    const float* qnb   = (const float*)d_in[4];
    const float* knw   = (const float*)d_in[5];
    const float* knb   = (const float*)d_in[6];
    const float* pw    = (const float*)d_in[7];
    const float* pb    = (const float*)d_in[8];
    float* out = (float*)d_out;

    // workspace layout (bytes)
    char* ws = (char*)d_ws;
    unsigned short* x_bf  = (unsigned short*)(ws + 0);          // 8.39 MB
    unsigned short* qw_bf = (unsigned short*)(ws + 8388608);    // 6.29 MB
    unsigned short* pw_bf = (unsigned short*)(ws + 14680064);   // 2.10 MB
    unsigned short* qbuf  = (unsigned short*)(ws + 16777216);   // 8.39 MB
    unsigned short* kbuf  = (unsigned short*)(ws + 25165824);   // 8.39 MB
    unsigned short* ao_bnc= (unsigned short*)(ws + 33554432);   // 8.39 MB
    unsigned short* vt    = (unsigned short*)(ws + 41943040);   // 8.39 MB
    unsigned long long* bmask = (unsigned long long*)(ws + 50331648);  // 1 MB

    // 0) fused casts -> contiguous [x_bf | qw_bf | pw_bf]
    cast_all_bf16<<<8388608 / 2048, 256, 0, stream>>>(x, qkv_w, pw, x_bf);

    // 0b) pack mask to bits (independent)
    pack_mask<<<(B_ * N_ * (N_ / 64)) / 4, 256, 0, stream>>>(mask, bmask);

    // 1) GEMM1 + fused LN + fused V-transpose -> qbuf/kbuf (sigma-d), vt
    gemm_qkv_ln<<<dim3(3072 / 128, 4096 / 128), 256, 0, stream>>>(
        x_bf, qw_bf, qnw, qnb, knw, knb, qbuf, kbuf, vt);

    // 2) masked flash attention v13 (64 q-rows/wave) -> ao bf16
    flash_attn_mfma13<<<dim3(N_ / 256, B_ * H_), 256, 0, stream>>>(
        qbuf, kbuf, vt, bmask, ao_bnc);

    // 3) out = ao @ proj_w^T + proj_b
    gemm_proj<<<dim3(DIM_ / 64, 4096 / 128), 256, 0, stream>>>(
        ao_bnc, pw_bf, pb, out);
}

// Round 9
// 258.698 us; speedup vs baseline: 1.1277x; 1.1277x over previous
//
#include <hip/hip_runtime.h>
#include <hip/hip_bf16.h>
#include <math.h>

#define B_    2
#define N_    2048
#define DIM_  1024
#define H_    16
#define HD_   64
#define EPS_  1e-5f
#define SCALE_ 0.125f   // HD_^-0.5
#define LOG2E_ 1.4426950408889634f
#define MFIX_  14.0f    // fixed softmax max (log2 domain); |logit| <= 11.7 hard bound

typedef __attribute__((ext_vector_type(8))) __bf16 bf16x8;
typedef __attribute__((ext_vector_type(8))) unsigned short ushort8;
typedef __attribute__((ext_vector_type(4))) float f32x4;
typedef __attribute__((ext_vector_type(4))) unsigned int uint4v;

__device__ __forceinline__ unsigned short f2bf(float x) {
    unsigned u = __builtin_bit_cast(unsigned, x);
    u += 0x7fff + ((u >> 16) & 1);   // RNE
    return (unsigned short)(u >> 16);
}
// pack two floats to bf16x2 with round-half-up (+0x8000) via v_perm
__device__ __forceinline__ unsigned pk2bf(float a, float b) {
    unsigned ua = __builtin_bit_cast(unsigned, a) + 0x8000u;
    unsigned ub = __builtin_bit_cast(unsigned, b) + 0x8000u;
    return __builtin_amdgcn_perm(ub, ua, 0x07060302);
}
// pack two floats to bf16x2 with RNE in ONE instruction (gfx950)
__device__ __forceinline__ unsigned cvtpk(float a, float b) {
    unsigned r;
    asm("v_cvt_pk_bf16_f32 %0, %1, %2" : "=v"(r) : "v"(a), "v"(b));
    return r;
}

__device__ __forceinline__ void gl_lds16(const void* g, void* l) {
    __builtin_amdgcn_global_load_lds(
        (const __attribute__((address_space(1))) void*)g,
        (__attribute__((address_space(3))) void*)l, 16, 0, 0);
}

// ---------------------------------------------------------------------------
// Fused [fp32->bf16 cast of x|qkv_w|proj_w] + [mask bit-pack] in ONE dispatch
// (block-uniform branch; saves a launch gap).
// ---------------------------------------------------------------------------
__global__ __launch_bounds__(256) void cast_and_pack(
    const float* __restrict__ x, const float* __restrict__ qkvw,
    const float* __restrict__ pw, const int* __restrict__ mask,
    unsigned short* __restrict__ out, unsigned long long* __restrict__ bm) {
    const int bid = blockIdx.x;
    if (bid < 4096) {
        int i = (bid * 256 + threadIdx.x) * 8;
        const float* src;
        if (i < 4194304) src = x + i;
        else if (i < 7340032) src = qkvw + (i - 4194304);
        else src = pw + (i - 7340032);
        float4 v0 = *(const float4*)src;
        float4 v1 = *(const float4*)(src + 4);
        ushort8 r;
        r[0] = f2bf(v0.x); r[1] = f2bf(v0.y); r[2] = f2bf(v0.z); r[3] = f2bf(v0.w);
        r[4] = f2bf(v1.x); r[5] = f2bf(v1.y); r[6] = f2bf(v1.z); r[7] = f2bf(v1.w);
        *(ushort8*)(out + i) = r;
    } else {
        int w = (bid - 4096) * 4 + (threadIdx.x >> 6);
        int lane = threadIdx.x & 63;
        int mv = mask[(size_t)w * 64 + lane];
        unsigned long long bits = __ballot(mv != 0);
        if (lane == 0) bm[w] = bits;
    }
}

// ---------------------------------------------------------------------------
// GEMM1 + fused LayerNorm epilogue + FUSED V-transpose (confirmed good, R4).
// Main loop now processes TWO 32-wide K-subtiles per barrier pair (32 barrier
// rounds instead of 64) — the 2-phase structure's vmcnt(0)+barrier drain is
// paid per round, so halving rounds cuts that stall. LDS layout stays
// [128][32] per subtile (64 B rows; a [128][64] layout would be a 16-way
// bank conflict and gl_lds forbids padding). LDS 32 KB -> 3 blocks/CU ok.
// ---------------------------------------------------------------------------
__global__ __launch_bounds__(256) void gemm_qkv_ln(
    const unsigned short* __restrict__ A, const unsigned short* __restrict__ Bw,
    const float* __restrict__ qnw, const float* __restrict__ qnb,
    const float* __restrict__ knw, const float* __restrict__ knb,
    unsigned short* __restrict__ qbuf, unsigned short* __restrict__ kbuf,
    unsigned short* __restrict__ vt) {
    const int K = DIM_;
    __shared__ unsigned short As[2 * 128 * 32];   // 16 KB
    __shared__ unsigned short Bs[2 * 128 * 32];   // 16 KB
    const int tid = threadIdx.x;
    const int wave = tid >> 6, lane = tid & 63;
    const int quad = lane >> 4, lcol = lane & 15;
    const int wr = wave >> 1, wc = wave & 1;
    const int row0 = blockIdx.y * 128, col0 = blockIdx.x * 128;

    f32x4 acc[4][4];
#pragma unroll
    for (int i = 0; i < 4; ++i)
#pragma unroll
        for (int j = 0; j < 4; ++j) acc[i][j] = (f32x4){0.f, 0.f, 0.f, 0.f};

    for (int k0 = 0; k0 < K; k0 += 64) {
        __syncthreads();
#pragma unroll
        for (int s = 0; s < 2; ++s) {
#pragma unroll
            for (int c = 0; c < 2; ++c) {
                int base = wave * 2048 + c * 1024;
                int myofs = base + lane * 16;
                int r = myofs >> 6;
                int kb = myofs & 63;
                gl_lds16((const char*)A +
                             ((size_t)(row0 + r) * K + k0 + s * 32) * 2 + kb,
                         (char*)As + s * 8192 + base);
                gl_lds16((const char*)Bw +
                             ((size_t)(col0 + r) * K + k0 + s * 32) * 2 + kb,
                         (char*)Bs + s * 8192 + base);
            }
        }
        __syncthreads();

#pragma unroll
        for (int s = 0; s < 2; ++s) {
            bf16x8 af[4], bfr[4];
#pragma unroll
            for (int i = 0; i < 4; ++i) {
                af[i] = *(const bf16x8*)&As[s * 4096 +
                                            (wr * 64 + i * 16 + lcol) * 32 + quad * 8];
                bfr[i] = *(const bf16x8*)&Bs[s * 4096 +
                                             (wc * 64 + i * 16 + lcol) * 32 + quad * 8];
            }
#pragma unroll
            for (int i = 0; i < 4; ++i)
#pragma unroll
                for (int j = 0; j < 4; ++j)
                    acc[i][j] = __builtin_amdgcn_mfma_f32_16x16x32_bf16(
                        af[i], bfr[j], acc[i][j], 0, 0, 0);
        }
    }

    const int colbase = col0 + wc * 64;      // wave-uniform, one head
    const int t = colbase >> 10;             // 0=q, 1=k, 2=v
    const int h = (colbase & 1023) >> 6;

    if (t < 2) {
        const float* wv = (t == 0) ? qnw : knw;
        const float* bv = (t == 0) ? qnb : knb;
        float wreg[4], breg[4];
#pragma unroll
        for (int j = 0; j < 4; ++j) {
            wreg[j] = wv[j * 16 + lcol];
            breg[j] = bv[j * 16 + lcol];
        }
        const float sc = (t == 0) ? (SCALE_ * LOG2E_) : 1.f;
        unsigned short* obase = (t == 0) ? qbuf : kbuf;
#pragma unroll
        for (int i = 0; i < 4; ++i) {
#pragma unroll
            for (int reg = 0; reg < 4; ++reg) {
                int row = row0 + wr * 64 + i * 16 + quad * 4 + reg;
                int bb = row >> 11, n = row & (N_ - 1);
                float v[4];
#pragma unroll
                for (int j = 0; j < 4; ++j) v[j] = acc[i][j][reg];
                float s = v[0] + v[1] + v[2] + v[3];
                s += __shfl_xor(s, 1);
                s += __shfl_xor(s, 2);
                s += __shfl_xor(s, 4);
                s += __shfl_xor(s, 8);
                float mu = s * (1.f / 64.f);
                float d[4], s2 = 0.f;
#pragma unroll
                for (int j = 0; j < 4; ++j) {
                    d[j] = v[j] - mu;
                    s2 += d[j] * d[j];
                }
                s2 += __shfl_xor(s2, 1);
                s2 += __shfl_xor(s2, 2);
                s2 += __shfl_xor(s2, 4);
                s2 += __shfl_xor(s2, 8);
                float r = rsqrtf(s2 * (1.f / 64.f) + EPS_);
                float o0 = (d[0] * r * wreg[0] + breg[0]) * sc;
                float o1 = (d[1] * r * wreg[1] + breg[1]) * sc;
                float o2 = (d[2] * r * wreg[2] + breg[2]) * sc;
                float o3 = (d[3] * r * wreg[3] + breg[3]) * sc;
                uint2 pk;
                pk.x = pk2bf(o0, o1);
                pk.y = pk2bf(o2, o3);
                // sigma store: positions lcol*4 + j, one uint2 per lane
                *(uint2*)(obase + ((size_t)(bb * H_ + h) * N_ + n) * 64 +
                          lcol * 4) = pk;
            }
        }
    } else {
        // V: fused transpose into vt (B,H,D,N), PV-ready key permutation.
        const int rowb = row0 + wr * 64;
        const int bb = rowb >> 11;
        unsigned short* vtb =
            vt + ((size_t)(bb * H_ + h) * 64) * (size_t)N_ + (rowb & (N_ - 1));
#pragma unroll
        for (int i = 0; i < 4; ++i) {
            const int pos = (i >> 1) * 32 + quad * 8 + (i & 1) * 4;
#pragma unroll
            for (int jj = 0; jj < 4; ++jj) {
                uint2 pk;
                pk.x = pk2bf(acc[i][jj][0], acc[i][jj][1]);
                pk.y = pk2bf(acc[i][jj][2], acc[i][jj][3]);
                *(uint2*)(vtb + (size_t)(lcol + 16 * jj) * N_ + pos) = pk;
            }
        }
    }
}

// ---------------------------------------------------------------------------
// Output projection GEMM: C[4096,1024] = A[4096,1024] * Bw[1024,1024]^T + b.
// Two K-subtiles per barrier pair (32 barrier rounds -> 16). LDS 24 KB, 2/CU.
// ---------------------------------------------------------------------------
__global__ __launch_bounds__(256) void gemm_proj(
    const unsigned short* __restrict__ A, const unsigned short* __restrict__ Bw,
    const float* __restrict__ bias, float* __restrict__ Cout) {
    const int K = DIM_;
    __shared__ unsigned short As[2 * 128 * 32];  // 16 KB, 2x8 planes
    __shared__ unsigned short Bs[2 * 64 * 32];   // 8 KB, 2x4 planes
    const int tid = threadIdx.x;
    const int wave = tid >> 6, lane = tid & 63;
    const int quad = lane >> 4, lcol = lane & 15;
    const int row0 = blockIdx.y * 128, col0 = blockIdx.x * 64;

    f32x4 acc[2][4];
#pragma unroll
    for (int i = 0; i < 2; ++i)
#pragma unroll
        for (int j = 0; j < 4; ++j) acc[i][j] = (f32x4){0.f, 0.f, 0.f, 0.f};

    for (int k0 = 0; k0 < K; k0 += 64) {
        __syncthreads();
#pragma unroll
        for (int pi = 0; pi < 6; ++pi) {
            int p = wave * 6 + pi;  // 24 planes: 0..15 = A (2 subs), 16..23 = B
            if (p < 16) {
                int s = p >> 3, q = p & 7;
                int base = q * 1024;
                int myofs = base + lane * 16;
                int r = myofs >> 6, kb = myofs & 63;
                gl_lds16((const char*)A +
                             ((size_t)(row0 + r) * K + k0 + s * 32) * 2 + kb,
                         (char*)As + s * 8192 + base);
            } else {
                int pp = p - 16;
                int s = pp >> 2, q = pp & 3;
                int base = q * 1024;
                int myofs = base + lane * 16;
                int r = myofs >> 6, kb = myofs & 63;
                gl_lds16((const char*)Bw +
                             ((size_t)(col0 + r) * K + k0 + s * 32) * 2 + kb,
                         (char*)Bs + s * 4096 + base);
            }
        }
        __syncthreads();

#pragma unroll
        for (int s = 0; s < 2; ++s) {
            bf16x8 af[2], bfr[4];
#pragma unroll
            for (int i = 0; i < 2; ++i)
                af[i] = *(const bf16x8*)&As[s * 4096 +
                                            (wave * 32 + i * 16 + lcol) * 32 + quad * 8];
#pragma unroll
            for (int j = 0; j < 4; ++j)
                bfr[j] = *(const bf16x8*)&Bs[s * 2048 +
                                             (j * 16 + lcol) * 32 + quad * 8];
#pragma unroll
            for (int i = 0; i < 2; ++i)
#pragma unroll
                for (int j = 0; j < 4; ++j)
                    acc[i][j] = __builtin_amdgcn_mfma_f32_16x16x32_bf16(
                        af[i], bfr[j], acc[i][j], 0, 0, 0);
        }
    }

#pragma unroll
    for (int i = 0; i < 2; ++i) {
#pragma unroll
        for (int j = 0; j < 4; ++j) {
            int col = col0 + j * 16 + lcol;
            float bv = bias[col];
#pragma unroll
            for (int reg = 0; reg < 4; ++reg) {
                int row = row0 + wave * 32 + i * 16 + quad * 4 + reg;
                Cout[(size_t)row * DIM_ + col] = acc[i][j][reg] + bv;
            }
        }
    }
}

// ---------------------------------------------------------------------------
// MFMA flash attention v9 — FROZEN at 83.4 us (best of v6..v13; v10/v12/v13
// all regressed: the 2-blocks/CU x 32-rows/wave point is a local optimum).
// ---------------------------------------------------------------------------
#define WAITBAR(Ncnt)                                                     \
    asm volatile("s_waitcnt vmcnt(" #Ncnt ")" ::: "memory");              \
    __builtin_amdgcn_s_barrier();                                         \
    __builtin_amdgcn_sched_barrier(0);

#define ISSUE2(B0, B1)                                                    \
    {                                                                     \
        gl_lds16(kp0, (char*)Ks[B0] + kld0);                              \
        gl_lds16(kp1, (char*)Ks[B0] + kld1);                              \
        gl_lds16(vp0, (char*)Vts[B0] + kld0);                             \
        gl_lds16(vp1, (char*)Vts[B0] + kld1);                             \
        gl_lds16(kp0 + 8192, (char*)Ks[B1] + kld0);                       \
        gl_lds16(kp1 + 8192, (char*)Ks[B1] + kld1);                       \
        gl_lds16(vp0 + 128, (char*)Vts[B1] + kld0);                       \
        gl_lds16(vp1 + 128, (char*)Vts[B1] + kld1);                       \
        mm0[B0] = bmq0[0]; mm1[B0] = bmq1[0];                             \
        mm0[B1] = bmq0[1]; mm1[B1] = bmq1[1];                             \
        kp0 += 16384; kp1 += 16384; vp0 += 256; vp1 += 256;               \
        bmq0 += 2; bmq1 += 2;                                             \
    }

#define QKT(J, SACC, MWA, MWB)                                            \
    {                                                                     \
        unsigned long long mqa = (MWA) >> (quad * 4);                     \
        unsigned long long mqb = (MWB) >> (quad * 4);                     \
        unsigned ml[2][2];                                                \
        ml[0][0] = (unsigned)mqa; ml[0][1] = (unsigned)(mqa >> 32);       \
        ml[1][0] = (unsigned)mqb; ml[1][1] = (unsigned)(mqb >> 32);       \
        _Pragma("unroll")                                                 \
        for (int qf = 0; qf < 2; ++qf)                                    \
            _Pragma("unroll")                                             \
            for (int kt = 0; kt < 4; ++kt) {                              \
                unsigned word = ml[qf][kt >> 1];                          \
                _Pragma("unroll")                                         \
                for (int reg = 0; reg < 4; ++reg) {                       \
                    unsigned msk = (unsigned)(((int)(word <<              \
                        (31 - ((kt & 1) * 16 + reg)))) >> 31);            \
                    SACC[qf][kt][reg] = __builtin_bit_cast(float,         \
                        (msk & 0xc61c4000u) | (~msk & 0xc1600000u));      \
                }                                                         \
            }                                                             \
        __builtin_amdgcn_s_setprio(1);                                    \
        _Pragma("unroll")                                                 \
        for (int kt = 0; kt < 4; ++kt)                                    \
            _Pragma("unroll")                                             \
            for (int d0 = 0; d0 < 2; ++d0) {                              \
                bf16x8 ak = *(const bf16x8*)((const char*)Ks[J] +         \
                    (d0 * 4 + quad) * 1024 + kt * 256 + lofs);            \
                SACC[0][kt] = __builtin_amdgcn_mfma_f32_16x16x32_bf16(    \
                    ak, bq[0][d0], SACC[0][kt], 0, 0, 0);                 \
                SACC[1][kt] = __builtin_amdgcn_mfma_f32_16x16x32_bf16(    \
                    ak, bq[1][d0], SACC[1][kt], 0, 0, 0);                 \
            }                                                             \
        __builtin_amdgcn_s_setprio(0);                                    \
    }

#define SM(SACC, PK)                                                      \
    _Pragma("unroll")                                                     \
    for (int qf = 0; qf < 2; ++qf)                                        \
        _Pragma("unroll")                                                 \
        for (int kt = 0; kt < 4; ++kt) {                                  \
            float p0 = exp2f(SACC[qf][kt][0]);                            \
            float p1 = exp2f(SACC[qf][kt][1]);                            \
            float p2 = exp2f(SACC[qf][kt][2]);                            \
            float p3 = exp2f(SACC[qf][kt][3]);                            \
            PK[qf][kt].x = cvtpk(p0, p1);                                 \
            PK[qf][kt].y = cvtpk(p2, p3);                                 \
        }

#define PV(J, PK)                                                         \
    {                                                                     \
        __builtin_amdgcn_s_setprio(1);                                    \
        _Pragma("unroll")                                                 \
        for (int P = 0; P < 2; ++P) {                                     \
            bf16x8 bp[2];                                                 \
            _Pragma("unroll")                                             \
            for (int qf = 0; qf < 2; ++qf) {                              \
                uint4v bu;                                                \
                bu[0] = PK[qf][2 * P].x;  bu[1] = PK[qf][2 * P].y;        \
                bu[2] = PK[qf][2 * P + 1].x; bu[3] = PK[qf][2 * P + 1].y; \
                bp[qf] = __builtin_bit_cast(bf16x8, bu);                  \
                lacc[qf] = __builtin_amdgcn_mfma_f32_16x16x32_bf16(       \
                    ones, bp[qf], lacc[qf], 0, 0, 0);                     \
            }                                                             \
            _Pragma("unroll")                                             \
            for (int dt = 0; dt < 4; ++dt) {                              \
                bf16x8 va = *(const bf16x8*)((const char*)Vts[J] +        \
                    (P * 4 + quad) * 1024 + dt * 256 + lofs);             \
                oacc[0][dt] = __builtin_amdgcn_mfma_f32_16x16x32_bf16(    \
                    va, bp[0], oacc[0][dt], 0, 0, 0);                     \
                oacc[1][dt] = __builtin_amdgcn_mfma_f32_16x16x32_bf16(    \
                    va, bp[1], oacc[1][dt], 0, 0, 0);                     \
            }                                                             \
        }                                                                 \
        __builtin_amdgcn_s_setprio(0);                                    \
    }

#define PAIR(J0, J1)                                                      \
    {                                                                     \
        f32x4 saccA[2][4], saccB[2][4];                                   \
        uint2 pkA[2][4], pkB[2][4];                                       \
        QKT(J0, saccA, mm0[J0], mm1[J0])                                  \
        SM(saccA, pkA)                                                    \
        QKT(J1, saccB, mm0[J1], mm1[J1])                                  \
        PV(J0, pkA)                                                       \
        SM(saccB, pkB)                                                    \
        PV(J1, pkB)                                                       \
    }

__global__ __launch_bounds__(256, 2) void flash_attn_mfma9(
    const unsigned short* __restrict__ q, const unsigned short* __restrict__ k,
    const unsigned short* __restrict__ vt,
    const unsigned long long* __restrict__ bm, unsigned short* __restrict__ ao) {
    __shared__ unsigned short Qs[128 * 64];       // 16 KB
    __shared__ unsigned short Ks[4][64 * 64];     // 32 KB
    __shared__ unsigned short Vts[4][64 * 64];    // 32 KB -> 80 KB total

    const int tid = threadIdx.x;
    const int wave = tid >> 6, lane = tid & 63;
    const int quad = lane >> 4, lcol = lane & 15;
    const int bh = blockIdx.y, b = bh >> 4, h = bh & 15;
    const int q0 = blockIdx.x * 128;
    const int lofs = (lcol ^ (quad * 2)) << 4;   // loop-invariant ds_read part

    const char* kgbase = (const char*)k + (size_t)bh * N_ * 128;
    const char* vtbase = (const char*)vt + (size_t)bh * 64 * N_ * 2;

    // per-wave staging (2 planes/wave for K and for V), incrementing pointers
    const int c0 = wave * 2, c1 = c0 + 1;
    const int swz0 = (c0 & 3) * 2, swz1 = (c1 & 3) * 2;
    const int kld0 = c0 * 1024, kld1 = c1 * 1024;
    const char* kp0 = kgbase + (lane ^ swz0) * 128 + c0 * 16;
    const char* kp1 = kgbase + (lane ^ swz1) * 128 + c1 * 16;
    const char* vp0 = vtbase + (size_t)(lane ^ swz0) * (N_ * 2) + c0 * 16;
    const char* vp1 = vtbase + (size_t)(lane ^ swz1) * (N_ * 2) + c1 * 16;

    const unsigned long long* bmq0 =
        bm + ((size_t)b * N_ + q0 + wave * 32 + lcol) * 32;
    const unsigned long long* bmq1 = bmq0 + 16 * 32;
    unsigned long long mm0[4], mm1[4];

    // ---- prologue: Q first (the 4 OLDEST vmem ops), then tiles 0..3
    {
        const char* qg = (const char*)(q + (size_t)(bh * N_ + q0) * 64);
#pragma unroll
        for (int c = 0; c < 4; ++c) {
            int base = wave * 4096 + c * 1024;
            gl_lds16(qg + base + lane * 16, (char*)Qs + base);
        }
    }
    asm volatile("" ::: "memory");
    __builtin_amdgcn_sched_barrier(0);
#pragma unroll
    for (int t = 0; t < 4; ++t) {
        gl_lds16(kp0, (char*)Ks[t] + kld0);
        gl_lds16(kp1, (char*)Ks[t] + kld1);
        gl_lds16(vp0, (char*)Vts[t] + kld0);
        gl_lds16(vp1, (char*)Vts[t] + kld1);
        mm0[t] = bmq0[t];
        mm1[t] = bmq1[t];
        kp0 += 8192; kp1 += 8192; vp0 += 128; vp1 += 128;
        __builtin_amdgcn_sched_barrier(0);
    }
    bmq0 += 4; bmq1 += 4;
    // wait own Q planes (28 outstanding; Q = 4 oldest). Each wave reads ONLY
    // its own staged Q planes -> no barrier needed here.
    asm volatile("s_waitcnt vmcnt(24)" ::: "memory");
    __builtin_amdgcn_sched_barrier(0);

    bf16x8 bq[2][2];
#pragma unroll
    for (int qf = 0; qf < 2; ++qf)
#pragma unroll
        for (int d0 = 0; d0 < 2; ++d0)
            bq[qf][d0] = *(const bf16x8*)&Qs[(wave * 32 + qf * 16 + lcol) * 64 +
                                             d0 * 32 + quad * 8];

    ushort8 ot;
#pragma unroll
    for (int i = 0; i < 8; ++i) ot[i] = 0x3F80;  // bf16 1.0
    const bf16x8 ones = __builtin_bit_cast(bf16x8, ot);

    f32x4 oacc[2][4];
#pragma unroll
    for (int qf = 0; qf < 2; ++qf)
#pragma unroll
        for (int dt = 0; dt < 4; ++dt) oacc[qf][dt] = (f32x4){0.f, 0.f, 0.f, 0.f};
    f32x4 lacc[2];
    lacc[0] = (f32x4){0.f, 0.f, 0.f, 0.f};
    lacc[1] = (f32x4){0.f, 0.f, 0.f, 0.f};

    // ---- 16 pair-bodies over 32 tiles
    WAITBAR(12)
    PAIR(0, 1)
    for (int g = 0; g < 7; ++g) {
        WAITBAR(0)
        ISSUE2(0, 1)
        PAIR(2, 3)
        WAITBAR(0)
        ISSUE2(2, 3)
        PAIR(0, 1)
    }
    WAITBAR(0)
    PAIR(2, 3)

#pragma unroll
    for (int qf = 0; qf < 2; ++qf) {
        float inv = 1.f / lacc[qf][0];
        int row = q0 + wave * 32 + qf * 16 + lcol;
        unsigned short* dst =
            ao + ((size_t)(b * N_ + row)) * DIM_ + h * 64 + quad * 4;
#pragma unroll
        for (int dt = 0; dt < 4; ++dt) {
            uint2 pko;
            pko.x = pk2bf(oacc[qf][dt][0] * inv, oacc[qf][dt][1] * inv);
            pko.y = pk2bf(oacc[qf][dt][2] * inv, oacc[qf][dt][3] * inv);
            *(uint2*)(dst + dt * 16) = pko;
        }
    }
}

// ---------------------------------------------------------------------------
extern "C" void kernel_launch(void* const* d_in, const int* in_sizes, int n_in,
                              void* d_out, int out_size, void* d_ws,
                              size_t ws_size, hipStream_t stream) {
    const float* x     = (const float*)d_in[0];
    const int*   mask  = (const int*)d_in[1];
    const float* qkv_w = (const float*)d_in[2];
    const float* qnw   = (const float*)d_in[3];
    const float* qnb   = (const float*)d_in[4];
    const float* knw   = (const float*)d_in[5];
    const float* knb   = (const float*)d_in[6];
    const float* pw    = (const float*)d_in[7];
    const float* pb    = (const float*)d_in[8];
    float* out = (float*)d_out;

    // workspace layout (bytes)
    char* ws = (char*)d_ws;
    unsigned short* x_bf  = (unsigned short*)(ws + 0);          // 8.39 MB
    unsigned short* qw_bf = (unsigned short*)(ws + 8388608);    // 6.29 MB
    unsigned short* pw_bf = (unsigned short*)(ws + 14680064);   // 2.10 MB
    unsigned short* qbuf  = (unsigned short*)(ws + 16777216);   // 8.39 MB
    unsigned short* kbuf  = (unsigned short*)(ws + 25165824);   // 8.39 MB
    unsigned short* ao_bnc= (unsigned short*)(ws + 33554432);   // 8.39 MB
    unsigned short* vt    = (unsigned short*)(ws + 41943040);   // 8.39 MB
    unsigned long long* bmask = (unsigned long long*)(ws + 50331648);  // 1 MB

    // 0) fused casts + mask pack (one dispatch)
    cast_and_pack<<<4096 + 32768, 256, 0, stream>>>(
        x, qkv_w, pw, mask, x_bf, bmask);

    // 1) GEMM1 + fused LN + fused V-transpose -> qbuf/kbuf (sigma-d), vt
    gemm_qkv_ln<<<dim3(3072 / 128, 4096 / 128), 256, 0, stream>>>(
        x_bf, qw_bf, qnw, qnb, knw, knb, qbuf, kbuf, vt);

    // 2) masked flash attention v9 (frozen best: 83.4 us) -> ao bf16
    flash_attn_mfma9<<<dim3(N_ / 128, B_ * H_), 256, 0, stream>>>(
        qbuf, kbuf, vt, bmask, ao_bnc);

    // 3) out = ao @ proj_w^T + proj_b
    gemm_proj<<<dim3(DIM_ / 64, 4096 / 128), 256, 0, stream>>>(
        ao_bnc, pw_bf, pb, out);
}

// Round 10
// 246.679 us; speedup vs baseline: 1.1827x; 1.0487x over previous
//
#include <hip/hip_runtime.h>
#include <hip/hip_bf16.h>
#include <math.h>

#define B_    2
#define N_    2048
#define DIM_  1024
#define H_    16
#define HD_   64
#define EPS_  1e-5f
#define SCALE_ 0.125f   // HD_^-0.5
#define LOG2E_ 1.4426950408889634f
#define MFIX_  14.0f    // fixed softmax max (log2 domain); |logit| <= 11.7 hard bound

typedef __attribute__((ext_vector_type(8))) __bf16 bf16x8;
typedef __attribute__((ext_vector_type(8))) unsigned short ushort8;
typedef __attribute__((ext_vector_type(4))) float f32x4;
typedef __attribute__((ext_vector_type(4))) unsigned int uint4v;

__device__ __forceinline__ unsigned short f2bf(float x) {
    unsigned u = __builtin_bit_cast(unsigned, x);
    u += 0x7fff + ((u >> 16) & 1);   // RNE
    return (unsigned short)(u >> 16);
}
// pack two floats to bf16x2 with round-half-up (+0x8000) via v_perm
__device__ __forceinline__ unsigned pk2bf(float a, float b) {
    unsigned ua = __builtin_bit_cast(unsigned, a) + 0x8000u;
    unsigned ub = __builtin_bit_cast(unsigned, b) + 0x8000u;
    return __builtin_amdgcn_perm(ub, ua, 0x07060302);
}
// pack two floats to bf16x2 with RNE in ONE instruction (gfx950)
__device__ __forceinline__ unsigned cvtpk(float a, float b) {
    unsigned r;
    asm("v_cvt_pk_bf16_f32 %0, %1, %2" : "=v"(r) : "v"(a), "v"(b));
    return r;
}

__device__ __forceinline__ void gl_lds16(const void* g, void* l) {
    __builtin_amdgcn_global_load_lds(
        (const __attribute__((address_space(1))) void*)g,
        (__attribute__((address_space(3))) void*)l, 16, 0, 0);
}

// ---------------------------------------------------------------------------
// Fused [fp32->bf16 cast of x|qkv_w|proj_w] + [mask bit-pack] in ONE dispatch.
// ---------------------------------------------------------------------------
__global__ __launch_bounds__(256) void cast_and_pack(
    const float* __restrict__ x, const float* __restrict__ qkvw,
    const float* __restrict__ pw, const int* __restrict__ mask,
    unsigned short* __restrict__ out, unsigned long long* __restrict__ bm) {
    const int bid = blockIdx.x;
    if (bid < 4096) {
        int i = (bid * 256 + threadIdx.x) * 8;
        const float* src;
        if (i < 4194304) src = x + i;
        else if (i < 7340032) src = qkvw + (i - 4194304);
        else src = pw + (i - 7340032);
        float4 v0 = *(const float4*)src;
        float4 v1 = *(const float4*)(src + 4);
        ushort8 r;
        r[0] = f2bf(v0.x); r[1] = f2bf(v0.y); r[2] = f2bf(v0.z); r[3] = f2bf(v0.w);
        r[4] = f2bf(v1.x); r[5] = f2bf(v1.y); r[6] = f2bf(v1.z); r[7] = f2bf(v1.w);
        *(ushort8*)(out + i) = r;
    } else {
        int w = (bid - 4096) * 4 + (threadIdx.x >> 6);
        int lane = threadIdx.x & 63;
        int mv = mask[(size_t)w * 64 + lane];
        unsigned long long bits = __ballot(mv != 0);
        if (lane == 0) bm[w] = bits;
    }
}

// ---------------------------------------------------------------------------
// Shared GEMM sync macro: loads issued a full compute-phase ago -> the
// vmcnt(0) drain is nearly free; one barrier per round.
// ---------------------------------------------------------------------------
#define GWB                                                               \
    asm volatile("s_waitcnt vmcnt(0)" ::: "memory");                      \
    __builtin_amdgcn_s_barrier();                                         \
    __builtin_amdgcn_sched_barrier(0);

// ---------------------------------------------------------------------------
// GEMM1 + fused LayerNorm epilogue + FUSED V-transpose (confirmed good, R4).
// Main loop restructured to the T3-minimum 2-phase prefetch: per 32-wide
// K-round, issue NEXT tile's global_load_lds BEFORE computing the current
// tile from the other LDS buffer, then a single vmcnt(0)+barrier. The loads
// land under the ~700-cyc MFMA phase instead of being drained cold (the R9
// structure exposed full load latency at its second barrier each round).
// WAR safety: buf written in round t was last read in round t-1; t-1's
// barrier orders it (flash-v9-proven discipline). LDS 2x16=32 KB.
// ---------------------------------------------------------------------------
#define QSTAGE(BUF, K0)                                                   \
    {                                                                     \
        _Pragma("unroll")                                                 \
        for (int c = 0; c < 2; ++c) {                                     \
            int pbase = wave * 2048 + c * 1024;                           \
            int myofs = pbase + lane * 16;                                \
            int r = myofs >> 6;                                           \
            int kb = myofs & 63;                                          \
            gl_lds16((const char*)A + ((size_t)(row0 + r) * K + (K0)) * 2 + kb, \
                     (char*)As[BUF] + pbase);                             \
            gl_lds16((const char*)Bw + ((size_t)(col0 + r) * K + (K0)) * 2 + kb, \
                     (char*)Bs[BUF] + pbase);                             \
        }                                                                 \
    }

#define QCOMPUTE(BUF)                                                     \
    {                                                                     \
        bf16x8 af[4], bfr[4];                                             \
        _Pragma("unroll")                                                 \
        for (int i = 0; i < 4; ++i) {                                     \
            af[i] = *(const bf16x8*)&As[BUF][(wr * 64 + i * 16 + lcol) * 32 + \
                                            quad * 8];                    \
            bfr[i] = *(const bf16x8*)&Bs[BUF][(wc * 64 + i * 16 + lcol) * 32 + \
                                             quad * 8];                   \
        }                                                                 \
        __builtin_amdgcn_s_setprio(1);                                    \
        _Pragma("unroll")                                                 \
        for (int i = 0; i < 4; ++i)                                       \
            _Pragma("unroll")                                             \
            for (int j = 0; j < 4; ++j)                                   \
                acc[i][j] = __builtin_amdgcn_mfma_f32_16x16x32_bf16(      \
                    af[i], bfr[j], acc[i][j], 0, 0, 0);                   \
        __builtin_amdgcn_s_setprio(0);                                    \
    }

__global__ __launch_bounds__(256) void gemm_qkv_ln(
    const unsigned short* __restrict__ A, const unsigned short* __restrict__ Bw,
    const float* __restrict__ qnw, const float* __restrict__ qnb,
    const float* __restrict__ knw, const float* __restrict__ knb,
    unsigned short* __restrict__ qbuf, unsigned short* __restrict__ kbuf,
    unsigned short* __restrict__ vt) {
    const int K = DIM_;
    __shared__ unsigned short As[2][128 * 32];   // 16 KB
    __shared__ unsigned short Bs[2][128 * 32];   // 16 KB
    const int tid = threadIdx.x;
    const int wave = tid >> 6, lane = tid & 63;
    const int quad = lane >> 4, lcol = lane & 15;
    const int wr = wave >> 1, wc = wave & 1;
    const int row0 = blockIdx.y * 128, col0 = blockIdx.x * 128;

    f32x4 acc[4][4];
#pragma unroll
    for (int i = 0; i < 4; ++i)
#pragma unroll
        for (int j = 0; j < 4; ++j) acc[i][j] = (f32x4){0.f, 0.f, 0.f, 0.f};

    // prologue: tile 0 -> buf 0
    QSTAGE(0, 0)
    GWB
    // 15 double-rounds (tiles 1..30 prefetched), tail does tiles 31 via
    // prefetch at K-32 then computes without further staging.
    for (int k0 = 0; k0 < K - 64; k0 += 64) {
        QSTAGE(1, k0 + 32)
        QCOMPUTE(0)
        GWB
        QSTAGE(0, k0 + 64)
        QCOMPUTE(1)
        GWB
    }
    QSTAGE(1, K - 32)
    QCOMPUTE(0)
    GWB
    QCOMPUTE(1)

    const int colbase = col0 + wc * 64;      // wave-uniform, one head
    const int t = colbase >> 10;             // 0=q, 1=k, 2=v
    const int h = (colbase & 1023) >> 6;

    if (t < 2) {
        const float* wv = (t == 0) ? qnw : knw;
        const float* bv = (t == 0) ? qnb : knb;
        float wreg[4], breg[4];
#pragma unroll
        for (int j = 0; j < 4; ++j) {
            wreg[j] = wv[j * 16 + lcol];
            breg[j] = bv[j * 16 + lcol];
        }
        const float sc = (t == 0) ? (SCALE_ * LOG2E_) : 1.f;
        unsigned short* obase = (t == 0) ? qbuf : kbuf;
#pragma unroll
        for (int i = 0; i < 4; ++i) {
#pragma unroll
            for (int reg = 0; reg < 4; ++reg) {
                int row = row0 + wr * 64 + i * 16 + quad * 4 + reg;
                int bb = row >> 11, n = row & (N_ - 1);
                float v[4];
#pragma unroll
                for (int j = 0; j < 4; ++j) v[j] = acc[i][j][reg];
                float s = v[0] + v[1] + v[2] + v[3];
                s += __shfl_xor(s, 1);
                s += __shfl_xor(s, 2);
                s += __shfl_xor(s, 4);
                s += __shfl_xor(s, 8);
                float mu = s * (1.f / 64.f);
                float d[4], s2 = 0.f;
#pragma unroll
                for (int j = 0; j < 4; ++j) {
                    d[j] = v[j] - mu;
                    s2 += d[j] * d[j];
                }
                s2 += __shfl_xor(s2, 1);
                s2 += __shfl_xor(s2, 2);
                s2 += __shfl_xor(s2, 4);
                s2 += __shfl_xor(s2, 8);
                float r = rsqrtf(s2 * (1.f / 64.f) + EPS_);
                float o0 = (d[0] * r * wreg[0] + breg[0]) * sc;
                float o1 = (d[1] * r * wreg[1] + breg[1]) * sc;
                float o2 = (d[2] * r * wreg[2] + breg[2]) * sc;
                float o3 = (d[3] * r * wreg[3] + breg[3]) * sc;
                uint2 pk;
                pk.x = pk2bf(o0, o1);
                pk.y = pk2bf(o2, o3);
                // sigma store: positions lcol*4 + j, one uint2 per lane
                *(uint2*)(obase + ((size_t)(bb * H_ + h) * N_ + n) * 64 +
                          lcol * 4) = pk;
            }
        }
    } else {
        // V: fused transpose into vt (B,H,D,N), PV-ready key permutation.
        const int rowb = row0 + wr * 64;
        const int bb = rowb >> 11;
        unsigned short* vtb =
            vt + ((size_t)(bb * H_ + h) * 64) * (size_t)N_ + (rowb & (N_ - 1));
#pragma unroll
        for (int i = 0; i < 4; ++i) {
            const int pos = (i >> 1) * 32 + quad * 8 + (i & 1) * 4;
#pragma unroll
            for (int jj = 0; jj < 4; ++jj) {
                uint2 pk;
                pk.x = pk2bf(acc[i][jj][0], acc[i][jj][1]);
                pk.y = pk2bf(acc[i][jj][2], acc[i][jj][3]);
                *(uint2*)(vtb + (size_t)(lcol + 16 * jj) * N_ + pos) = pk;
            }
        }
    }
}

// ---------------------------------------------------------------------------
// Output projection GEMM with the same 2-phase prefetch. LDS 2x12=24 KB.
// ---------------------------------------------------------------------------
#define PSTAGE(BUF, K0)                                                   \
    {                                                                     \
        _Pragma("unroll")                                                 \
        for (int pi = 0; pi < 3; ++pi) {                                  \
            int p = wave * 3 + pi;  /* 12 planes: 0..7 = A, 8..11 = B */  \
            if (p < 8) {                                                  \
                int pbase = p * 1024;                                     \
                int myofs = pbase + lane * 16;                            \
                int r = myofs >> 6, kb = myofs & 63;                      \
                gl_lds16((const char*)A +                                 \
                             ((size_t)(row0 + r) * K + (K0)) * 2 + kb,    \
                         (char*)As[BUF] + pbase);                         \
            } else {                                                      \
                int pbase = (p - 8) * 1024;                               \
                int myofs = pbase + lane * 16;                            \
                int r = myofs >> 6, kb = myofs & 63;                      \
                gl_lds16((const char*)Bw +                                \
                             ((size_t)(col0 + r) * K + (K0)) * 2 + kb,    \
                         (char*)Bs[BUF] + pbase);                         \
            }                                                             \
        }                                                                 \
    }

#define PCOMPUTE(BUF)                                                     \
    {                                                                     \
        bf16x8 af[2], bfr[4];                                             \
        _Pragma("unroll")                                                 \
        for (int i = 0; i < 2; ++i)                                       \
            af[i] = *(const bf16x8*)&As[BUF][(wave * 32 + i * 16 + lcol) * 32 + \
                                            quad * 8];                    \
        _Pragma("unroll")                                                 \
        for (int j = 0; j < 4; ++j)                                       \
            bfr[j] = *(const bf16x8*)&Bs[BUF][(j * 16 + lcol) * 32 + quad * 8]; \
        __builtin_amdgcn_s_setprio(1);                                    \
        _Pragma("unroll")                                                 \
        for (int i = 0; i < 2; ++i)                                       \
            _Pragma("unroll")                                             \
            for (int j = 0; j < 4; ++j)                                   \
                acc[i][j] = __builtin_amdgcn_mfma_f32_16x16x32_bf16(      \
                    af[i], bfr[j], acc[i][j], 0, 0, 0);                   \
        __builtin_amdgcn_s_setprio(0);                                    \
    }

__global__ __launch_bounds__(256) void gemm_proj(
    const unsigned short* __restrict__ A, const unsigned short* __restrict__ Bw,
    const float* __restrict__ bias, float* __restrict__ Cout) {
    const int K = DIM_;
    __shared__ unsigned short As[2][128 * 32];  // 16 KB
    __shared__ unsigned short Bs[2][64 * 32];   // 8 KB
    const int tid = threadIdx.x;
    const int wave = tid >> 6, lane = tid & 63;
    const int quad = lane >> 4, lcol = lane & 15;
    const int row0 = blockIdx.y * 128, col0 = blockIdx.x * 64;

    f32x4 acc[2][4];
#pragma unroll
    for (int i = 0; i < 2; ++i)
#pragma unroll
        for (int j = 0; j < 4; ++j) acc[i][j] = (f32x4){0.f, 0.f, 0.f, 0.f};

    PSTAGE(0, 0)
    GWB
    for (int k0 = 0; k0 < K - 64; k0 += 64) {
        PSTAGE(1, k0 + 32)
        PCOMPUTE(0)
        GWB
        PSTAGE(0, k0 + 64)
        PCOMPUTE(1)
        GWB
    }
    PSTAGE(1, K - 32)
    PCOMPUTE(0)
    GWB
    PCOMPUTE(1)

#pragma unroll
    for (int i = 0; i < 2; ++i) {
#pragma unroll
        for (int j = 0; j < 4; ++j) {
            int col = col0 + j * 16 + lcol;
            float bv = bias[col];
#pragma unroll
            for (int reg = 0; reg < 4; ++reg) {
                int row = row0 + wave * 32 + i * 16 + quad * 4 + reg;
                Cout[(size_t)row * DIM_ + col] = acc[i][j][reg] + bv;
            }
        }
    }
}

// ---------------------------------------------------------------------------
// MFMA flash attention v9 — FROZEN at 83.4 us (best of v6..v13; v10/v12/v13
// all regressed: the 2-blocks/CU x 32-rows/wave point is a local optimum).
// NOTE R9 anomaly: identical code profiled 102.9 us in the R9 session with
// ALL rates uniformly ~0.81x (incl. hbm_gbps at same FETCH_SIZE) — chip
// clock-state difference between sessions, not a code effect.
// ---------------------------------------------------------------------------
#define WAITBAR(Ncnt)                                                     \
    asm volatile("s_waitcnt vmcnt(" #Ncnt ")" ::: "memory");              \
    __builtin_amdgcn_s_barrier();                                         \
    __builtin_amdgcn_sched_barrier(0);

#define ISSUE2(B0, B1)                                                    \
    {                                                                     \
        gl_lds16(kp0, (char*)Ks[B0] + kld0);                              \
        gl_lds16(kp1, (char*)Ks[B0] + kld1);                              \
        gl_lds16(vp0, (char*)Vts[B0] + kld0);                             \
        gl_lds16(vp1, (char*)Vts[B0] + kld1);                             \
        gl_lds16(kp0 + 8192, (char*)Ks[B1] + kld0);                       \
        gl_lds16(kp1 + 8192, (char*)Ks[B1] + kld1);                       \
        gl_lds16(vp0 + 128, (char*)Vts[B1] + kld0);                       \
        gl_lds16(vp1 + 128, (char*)Vts[B1] + kld1);                       \
        mm0[B0] = bmq0[0]; mm1[B0] = bmq1[0];                             \
        mm0[B1] = bmq0[1]; mm1[B1] = bmq1[1];                             \
        kp0 += 16384; kp1 += 16384; vp0 += 256; vp1 += 256;               \
        bmq0 += 2; bmq1 += 2;                                             \
    }

#define QKT(J, SACC, MWA, MWB)                                            \
    {                                                                     \
        unsigned long long mqa = (MWA) >> (quad * 4);                     \
        unsigned long long mqb = (MWB) >> (quad * 4);                     \
        unsigned ml[2][2];                                                \
        ml[0][0] = (unsigned)mqa; ml[0][1] = (unsigned)(mqa >> 32);       \
        ml[1][0] = (unsigned)mqb; ml[1][1] = (unsigned)(mqb >> 32);       \
        _Pragma("unroll")                                                 \
        for (int qf = 0; qf < 2; ++qf)                                    \
            _Pragma("unroll")                                             \
            for (int kt = 0; kt < 4; ++kt) {                              \
                unsigned word = ml[qf][kt >> 1];                          \
                _Pragma("unroll")                                         \
                for (int reg = 0; reg < 4; ++reg) {                       \
                    unsigned msk = (unsigned)(((int)(word <<              \
                        (31 - ((kt & 1) * 16 + reg)))) >> 31);            \
                    SACC[qf][kt][reg] = __builtin_bit_cast(float,         \
                        (msk & 0xc61c4000u) | (~msk & 0xc1600000u));      \
                }                                                         \
            }                                                             \
        __builtin_amdgcn_s_setprio(1);                                    \
        _Pragma("unroll")                                                 \
        for (int kt = 0; kt < 4; ++kt)                                    \
            _Pragma("unroll")                                             \
            for (int d0 = 0; d0 < 2; ++d0) {                              \
                bf16x8 ak = *(const bf16x8*)((const char*)Ks[J] +         \
                    (d0 * 4 + quad) * 1024 + kt * 256 + lofs);            \
                SACC[0][kt] = __builtin_amdgcn_mfma_f32_16x16x32_bf16(    \
                    ak, bq[0][d0], SACC[0][kt], 0, 0, 0);                 \
                SACC[1][kt] = __builtin_amdgcn_mfma_f32_16x16x32_bf16(    \
                    ak, bq[1][d0], SACC[1][kt], 0, 0, 0);                 \
            }                                                             \
        __builtin_amdgcn_s_setprio(0);                                    \
    }

#define SM(SACC, PK)                                                      \
    _Pragma("unroll")                                                     \
    for (int qf = 0; qf < 2; ++qf)                                        \
        _Pragma("unroll")                                                 \
        for (int kt = 0; kt < 4; ++kt) {                                  \
            float p0 = exp2f(SACC[qf][kt][0]);                            \
            float p1 = exp2f(SACC[qf][kt][1]);                            \
            float p2 = exp2f(SACC[qf][kt][2]);                            \
            float p3 = exp2f(SACC[qf][kt][3]);                            \
            PK[qf][kt].x = cvtpk(p0, p1);                                 \
            PK[qf][kt].y = cvtpk(p2, p3);                                 \
        }

#define PV(J, PK)                                                         \
    {                                                                     \
        __builtin_amdgcn_s_setprio(1);                                    \
        _Pragma("unroll")                                                 \
        for (int P = 0; P < 2; ++P) {                                     \
            bf16x8 bp[2];                                                 \
            _Pragma("unroll")                                             \
            for (int qf = 0; qf < 2; ++qf) {                              \
                uint4v bu;                                                \
                bu[0] = PK[qf][2 * P].x;  bu[1] = PK[qf][2 * P].y;        \
                bu[2] = PK[qf][2 * P + 1].x; bu[3] = PK[qf][2 * P + 1].y; \
                bp[qf] = __builtin_bit_cast(bf16x8, bu);                  \
                lacc[qf] = __builtin_amdgcn_mfma_f32_16x16x32_bf16(       \
                    ones, bp[qf], lacc[qf], 0, 0, 0);                     \
            }                                                             \
            _Pragma("unroll")                                             \
            for (int dt = 0; dt < 4; ++dt) {                              \
                bf16x8 va = *(const bf16x8*)((const char*)Vts[J] +        \
                    (P * 4 + quad) * 1024 + dt * 256 + lofs);             \
                oacc[0][dt] = __builtin_amdgcn_mfma_f32_16x16x32_bf16(    \
                    va, bp[0], oacc[0][dt], 0, 0, 0);                     \
                oacc[1][dt] = __builtin_amdgcn_mfma_f32_16x16x32_bf16(    \
                    va, bp[1], oacc[1][dt], 0, 0, 0);                     \
            }                                                             \
        }                                                                 \
        __builtin_amdgcn_s_setprio(0);                                    \
    }

#define PAIR(J0, J1)                                                      \
    {                                                                     \
        f32x4 saccA[2][4], saccB[2][4];                                   \
        uint2 pkA[2][4], pkB[2][4];                                       \
        QKT(J0, saccA, mm0[J0], mm1[J0])                                  \
        SM(saccA, pkA)                                                    \
        QKT(J1, saccB, mm0[J1], mm1[J1])                                  \
        PV(J0, pkA)                                                       \
        SM(saccB, pkB)                                                    \
        PV(J1, pkB)                                                       \
    }

__global__ __launch_bounds__(256, 2) void flash_attn_mfma9(
    const unsigned short* __restrict__ q, const unsigned short* __restrict__ k,
    const unsigned short* __restrict__ vt,
    const unsigned long long* __restrict__ bm, unsigned short* __restrict__ ao) {
    __shared__ unsigned short Qs[128 * 64];       // 16 KB
    __shared__ unsigned short Ks[4][64 * 64];     // 32 KB
    __shared__ unsigned short Vts[4][64 * 64];    // 32 KB -> 80 KB total

    const int tid = threadIdx.x;
    const int wave = tid >> 6, lane = tid & 63;
    const int quad = lane >> 4, lcol = lane & 15;
    const int bh = blockIdx.y, b = bh >> 4, h = bh & 15;
    const int q0 = blockIdx.x * 128;
    const int lofs = (lcol ^ (quad * 2)) << 4;   // loop-invariant ds_read part

    const char* kgbase = (const char*)k + (size_t)bh * N_ * 128;
    const char* vtbase = (const char*)vt + (size_t)bh * 64 * N_ * 2;

    // per-wave staging (2 planes/wave for K and for V), incrementing pointers
    const int c0 = wave * 2, c1 = c0 + 1;
    const int swz0 = (c0 & 3) * 2, swz1 = (c1 & 3) * 2;
    const int kld0 = c0 * 1024, kld1 = c1 * 1024;
    const char* kp0 = kgbase + (lane ^ swz0) * 128 + c0 * 16;
    const char* kp1 = kgbase + (lane ^ swz1) * 128 + c1 * 16;
    const char* vp0 = vtbase + (size_t)(lane ^ swz0) * (N_ * 2) + c0 * 16;
    const char* vp1 = vtbase + (size_t)(lane ^ swz1) * (N_ * 2) + c1 * 16;

    const unsigned long long* bmq0 =
        bm + ((size_t)b * N_ + q0 + wave * 32 + lcol) * 32;
    const unsigned long long* bmq1 = bmq0 + 16 * 32;
    unsigned long long mm0[4], mm1[4];

    // ---- prologue: Q first (the 4 OLDEST vmem ops), then tiles 0..3
    {
        const char* qg = (const char*)(q + (size_t)(bh * N_ + q0) * 64);
#pragma unroll
        for (int c = 0; c < 4; ++c) {
            int base = wave * 4096 + c * 1024;
            gl_lds16(qg + base + lane * 16, (char*)Qs + base);
        }
    }
    asm volatile("" ::: "memory");
    __builtin_amdgcn_sched_barrier(0);
#pragma unroll
    for (int t = 0; t < 4; ++t) {
        gl_lds16(kp0, (char*)Ks[t] + kld0);
        gl_lds16(kp1, (char*)Ks[t] + kld1);
        gl_lds16(vp0, (char*)Vts[t] + kld0);
        gl_lds16(vp1, (char*)Vts[t] + kld1);
        mm0[t] = bmq0[t];
        mm1[t] = bmq1[t];
        kp0 += 8192; kp1 += 8192; vp0 += 128; vp1 += 128;
        __builtin_amdgcn_sched_barrier(0);
    }
    bmq0 += 4; bmq1 += 4;
    // wait own Q planes (28 outstanding; Q = 4 oldest). Each wave reads ONLY
    // its own staged Q planes -> no barrier needed here.
    asm volatile("s_waitcnt vmcnt(24)" ::: "memory");
    __builtin_amdgcn_sched_barrier(0);

    bf16x8 bq[2][2];
#pragma unroll
    for (int qf = 0; qf < 2; ++qf)
#pragma unroll
        for (int d0 = 0; d0 < 2; ++d0)
            bq[qf][d0] = *(const bf16x8*)&Qs[(wave * 32 + qf * 16 + lcol) * 64 +
                                             d0 * 32 + quad * 8];

    ushort8 ot;
#pragma unroll
    for (int i = 0; i < 8; ++i) ot[i] = 0x3F80;  // bf16 1.0
    const bf16x8 ones = __builtin_bit_cast(bf16x8, ot);

    f32x4 oacc[2][4];
#pragma unroll
    for (int qf = 0; qf < 2; ++qf)
#pragma unroll
        for (int dt = 0; dt < 4; ++dt) oacc[qf][dt] = (f32x4){0.f, 0.f, 0.f, 0.f};
    f32x4 lacc[2];
    lacc[0] = (f32x4){0.f, 0.f, 0.f, 0.f};
    lacc[1] = (f32x4){0.f, 0.f, 0.f, 0.f};

    // ---- 16 pair-bodies over 32 tiles
    WAITBAR(12)
    PAIR(0, 1)
    for (int g = 0; g < 7; ++g) {
        WAITBAR(0)
        ISSUE2(0, 1)
        PAIR(2, 3)
        WAITBAR(0)
        ISSUE2(2, 3)
        PAIR(0, 1)
    }
    WAITBAR(0)
    PAIR(2, 3)

#pragma unroll
    for (int qf = 0; qf < 2; ++qf) {
        float inv = 1.f / lacc[qf][0];
        int row = q0 + wave * 32 + qf * 16 + lcol;
        unsigned short* dst =
            ao + ((size_t)(b * N_ + row)) * DIM_ + h * 64 + quad * 4;
#pragma unroll
        for (int dt = 0; dt < 4; ++dt) {
            uint2 pko;
            pko.x = pk2bf(oacc[qf][dt][0] * inv, oacc[qf][dt][1] * inv);
            pko.y = pk2bf(oacc[qf][dt][2] * inv, oacc[qf][dt][3] * inv);
            *(uint2*)(dst + dt * 16) = pko;
        }
    }
}

// ---------------------------------------------------------------------------
extern "C" void kernel_launch(void* const* d_in, const int* in_sizes, int n_in,
                              void* d_out, int out_size, void* d_ws,
                              size_t ws_size, hipStream_t stream) {
    const float* x     = (const float*)d_in[0];
    const int*   mask  = (const int*)d_in[1];
    const float* qkv_w = (const float*)d_in[2];
    const float* qnw   = (const float*)d_in[3];
    const float* qnb   = (const float*)d_in[4];
    const float* knw   = (const float*)d_in[5];
    const float* knb   = (const float*)d_in[6];
    const float* pw    = (const float*)d_in[7];
    const float* pb    = (const float*)d_in[8];
    float* out = (float*)d_out;

    // workspace layout (bytes)
    char* ws = (char*)d_ws;
    unsigned short* x_bf  = (unsigned short*)(ws + 0);          // 8.39 MB
    unsigned short* qw_bf = (unsigned short*)(ws + 8388608);    // 6.29 MB
    unsigned short* pw_bf = (unsigned short*)(ws + 14680064);   // 2.10 MB
    unsigned short* qbuf  = (unsigned short*)(ws + 16777216);   // 8.39 MB
    unsigned short* kbuf  = (unsigned short*)(ws + 25165824);   // 8.39 MB
    unsigned short* ao_bnc= (unsigned short*)(ws + 33554432);   // 8.39 MB
    unsigned short* vt    = (unsigned short*)(ws + 41943040);   // 8.39 MB
    unsigned long long* bmask = (unsigned long long*)(ws + 50331648);  // 1 MB

    // 0) fused casts + mask pack (one dispatch)
    cast_and_pack<<<4096 + 32768, 256, 0, stream>>>(
        x, qkv_w, pw, mask, x_bf, bmask);

    // 1) GEMM1 + fused LN + fused V-transpose (2-phase prefetch)
    gemm_qkv_ln<<<dim3(3072 / 128, 4096 / 128), 256, 0, stream>>>(
        x_bf, qw_bf, qnw, qnb, knw, knb, qbuf, kbuf, vt);

    // 2) masked flash attention v9 (frozen best: 83.4 us) -> ao bf16
    flash_attn_mfma9<<<dim3(N_ / 128, B_ * H_), 256, 0, stream>>>(
        qbuf, kbuf, vt, bmask, ao_bnc);

    // 3) out = ao @ proj_w^T + proj_b (2-phase prefetch)
    gemm_proj<<<dim3(DIM_ / 64, 4096 / 128), 256, 0, stream>>>(
        ao_bnc, pw_bf, pb, out);
}